// Round 4
// baseline (546.903 us; speedup 1.0000x reference)
//
#include <hip/hip_runtime.h>
#include <hip/hip_bf16.h>
#include <stdint.h>

// GnnActor fused deepset actor. INPUTS/OUTPUTS ARE FLOAT32 (reference dtype).
// Internally: convert to bf16 at LDS staging, MFMA bf16 with f32 accum,
// biases added in f32, output stored f32.
//  node_kernel: per (32-row batch tile, 6-node half):
//    build inp-tile(32x320) bf16 in LDS [body|obj/iso|segmax(8 edges)/isofeat]
//    -> GEMM1(K=320,relu,b1) -> h-tile LDS -> GEMM2(K=256,relu,b2)
//    -> f32 reg pool over 6 nodes -> atomicAdd into g_pooled (f32)
//  rho_heads: g_pooled -> GEMM3(K=256,relu,br) -> heads(N=64) -> clip -> out
// Scratch in module __device__ arrays (no d_ws use; graph-safe).

#define Bsz   8192
#define OBSW  1216      // 64 + 9*128
#define NH    256

typedef unsigned short u16;
typedef unsigned int   u32;

using bf16x8 = __attribute__((ext_vector_type(8))) short;
using f32x4  = __attribute__((ext_vector_type(4))) float;

// ---- module-scope scratch (~8.45 MB .bss) ----
__device__ u16   g_W1t[256 * 320];   // bf16(W1)^T  (N=256 rows, K=320)
__device__ u16   g_W2t[256 * 256];   // bf16(W2)^T
__device__ u16   g_Rt [256 * 256];   // bf16(Wrho)^T
__device__ u16   g_Wcat[64 * 256];   // [bf16(Wm)^T ; bf16(Ws)^T]
__device__ float g_pooled[Bsz * NH]; // f32 pooled accumulator

__device__ __forceinline__ u16 f2bf(float f) {
  union { float f; u32 i; } v; v.f = f;
  u32 x = v.i;
  x += 0x7fffu + ((x >> 16) & 1u);   // RNE; values here are finite
  return (u16)(x >> 16);
}
__device__ __forceinline__ uint4 pack8(const float* f) {
  uint4 o;
  o.x = (u32)f2bf(f[0]) | ((u32)f2bf(f[1]) << 16);
  o.y = (u32)f2bf(f[2]) | ((u32)f2bf(f[3]) << 16);
  o.z = (u32)f2bf(f[4]) | ((u32)f2bf(f[5]) << 16);
  o.w = (u32)f2bf(f[6]) | ((u32)f2bf(f[7]) << 16);
  return o;
}
__device__ __forceinline__ void load8f(const float* p, float* f) {
  *(float4*)(f)     = *(const float4*)(p);
  *(float4*)(f + 4) = *(const float4*)(p + 4);
}

// ---------------- weight transpose+cast: f32 in[K][N] -> bf16 g_*[N][K] --------
// dst: 0=g_W1t 1=g_W2t 2=g_Rt 3=g_Wcat(+row_off rows)
__global__ void transpose_cast(const float* __restrict__ in, int dst,
                               int K, int N, int row_off) {
  __shared__ u16 tile[32][33];
  u16* out = (dst == 0) ? g_W1t : (dst == 1) ? g_W2t : (dst == 2) ? g_Rt : g_Wcat;
  int k0 = blockIdx.x * 32, n0 = blockIdx.y * 32;
  int c = threadIdx.x & 31, r0 = threadIdx.x >> 5;
  #pragma unroll
  for (int i = 0; i < 4; i++) {
    int r = r0 + i * 8;
    tile[r][c] = f2bf(in[(size_t)(k0 + r) * N + (n0 + c)]);
  }
  __syncthreads();
  #pragma unroll
  for (int i = 0; i < 4; i++) {
    int r = r0 + i * 8;
    out[(size_t)(n0 + r + row_off) * K + (k0 + c)] = tile[c][r];
  }
}

__global__ void zero_pooled() {
  size_t t = (size_t)blockIdx.x * 256 + threadIdx.x;
  float4 z = {0.f, 0.f, 0.f, 0.f};
  *(float4*)(g_pooled + t * 4) = z;
}

// ---------------- fused node kernel --------------------------------------------
// grid = (Bsz/32) * 2; block (btile, nhalf) handles nodes nhalf*6..+6.
__global__ __launch_bounds__(256)
void node_kernel(const float* __restrict__ obs, const float* __restrict__ ef,
                 const float* __restrict__ iso, const float* __restrict__ isof,
                 const float* __restrict__ b1, const float* __restrict__ b2) {
  __shared__ __attribute__((aligned(16))) u16 As[32][72];
  __shared__ __attribute__((aligned(16))) u16 Bs[256][72];
  __shared__ __attribute__((aligned(16))) u16 Ht[32][264];
  const int btile = blockIdx.x >> 1;
  const int nhalf = blockIdx.x & 1;
  const int b0 = btile * 32;
  const int tid = threadIdx.x;
  const int wave = tid >> 6, lane = tid & 63;
  const int nw = wave * 64, lrow = lane & 15, quad = lane >> 4;
  const int srow = tid >> 3, sck = (tid & 7) * 8;
  const size_t sb = (size_t)(b0 + srow);

  const f32x4 vzero = {0.f, 0.f, 0.f, 0.f};
  f32x4 pool[2][4];
  #pragma unroll
  for (int a = 0; a < 2; a++)
    #pragma unroll
    for (int b = 0; b < 4; b++) pool[a][b] = vzero;

  for (int nn = 0; nn < 6; nn++) {
    const int n = nhalf * 6 + nn;
    f32x4 acc[2][4];
    #pragma unroll
    for (int a = 0; a < 2; a++)
      #pragma unroll
      for (int b = 0; b < 4; b++) acc[a][b] = vzero;

    // ---- GEMM1: K=320 in 5 steps of 64 -------------------------------------
    for (int step = 0; step < 5; step++) {
      float f[8];
      if (step == 0) {                      // body dims 0..63
        load8f(obs + sb * OBSW + sck, f);
      } else if (step <= 2) {               // object/iso node dims
        int kk = (step - 1) * 64 + sck;
        const float* p = (n < 9) ? obs + sb * OBSW + 64 + n * 128 + kk
                                 : iso + (sb * 3 + (n - 9)) * 128 + kk;
        load8f(p, f);
      } else {                              // segmax over 8 edges / iso feats
        int kk = (step - 3) * 64 + sck;
        if (n < 9) {
          const float* base = ef + (sb * 72 + n) * 128 + kk;  // edge e = n + 9j
          load8f(base, f);
          #pragma unroll
          for (int j = 1; j < 8; j++) {
            float w[8];
            load8f(base + (size_t)j * 1152, w);
            #pragma unroll
            for (int q = 0; q < 8; q++) f[q] = fmaxf(f[q], w[q]);
          }
        } else {
          load8f(isof + (sb * 3 + (n - 9)) * 128 + kk, f);
        }
      }
      *(uint4*)(&As[srow][sck]) = pack8(f);
      #pragma unroll
      for (int i = 0; i < 8; i++) {
        int row = srow + i * 32;
        *(uint4*)(&Bs[row][sck]) =
            *(const uint4*)(g_W1t + (size_t)row * 320 + step * 64 + sck);
      }
      __syncthreads();
      #pragma unroll
      for (int ks = 0; ks < 2; ks++) {
        int kk = ks * 32 + quad * 8;
        bf16x8 af[2], bq[4];
        af[0] = *(const bf16x8*)(&As[lrow][kk]);
        af[1] = *(const bf16x8*)(&As[16 + lrow][kk]);
        #pragma unroll
        for (int nb = 0; nb < 4; nb++)
          bq[nb] = *(const bf16x8*)(&Bs[nw + nb * 16 + lrow][kk]);
        #pragma unroll
        for (int mb = 0; mb < 2; mb++)
          #pragma unroll
          for (int nb = 0; nb < 4; nb++)
            acc[mb][nb] = __builtin_amdgcn_mfma_f32_16x16x32_bf16(
                af[mb], bq[nb], acc[mb][nb], 0, 0, 0);
      }
      __syncthreads();
    }
    // epilogue 1: Ht = bf16(relu(acc + b1))  (D: row=quad*4+i, col=lane&15)
    #pragma unroll
    for (int nb = 0; nb < 4; nb++) {
      int col = nw + nb * 16 + lrow;
      float bv = b1[col];
      #pragma unroll
      for (int mb = 0; mb < 2; mb++)
        #pragma unroll
        for (int i = 0; i < 4; i++)
          Ht[mb * 16 + quad * 4 + i][col] = f2bf(fmaxf(acc[mb][nb][i] + bv, 0.f));
    }
    #pragma unroll
    for (int a = 0; a < 2; a++)
      #pragma unroll
      for (int b = 0; b < 4; b++) acc[a][b] = vzero;

    // ---- GEMM2: K=256 in 4 steps of 64 -------------------------------------
    for (int k0 = 0; k0 < 256; k0 += 64) {
      #pragma unroll
      for (int i = 0; i < 8; i++) {
        int row = srow + i * 32;
        *(uint4*)(&Bs[row][sck]) =
            *(const uint4*)(g_W2t + (size_t)row * 256 + k0 + sck);
      }
      __syncthreads();   // covers Ht writes (first iter) + Bs staging
      #pragma unroll
      for (int ks = 0; ks < 2; ks++) {
        int kk = ks * 32 + quad * 8;
        bf16x8 af[2], bq[4];
        af[0] = *(const bf16x8*)(&Ht[lrow][k0 + kk]);
        af[1] = *(const bf16x8*)(&Ht[16 + lrow][k0 + kk]);
        #pragma unroll
        for (int nb = 0; nb < 4; nb++)
          bq[nb] = *(const bf16x8*)(&Bs[nw + nb * 16 + lrow][kk]);
        #pragma unroll
        for (int mb = 0; mb < 2; mb++)
          #pragma unroll
          for (int nb = 0; nb < 4; nb++)
            acc[mb][nb] = __builtin_amdgcn_mfma_f32_16x16x32_bf16(
                af[mb], bq[nb], acc[mb][nb], 0, 0, 0);
      }
      __syncthreads();
    }
    // epilogue 2: pool += relu(acc + b2)
    #pragma unroll
    for (int nb = 0; nb < 4; nb++) {
      int col = nw + nb * 16 + lrow;
      float bv = b2[col];
      #pragma unroll
      for (int mb = 0; mb < 2; mb++)
        #pragma unroll
        for (int i = 0; i < 4; i++)
          pool[mb][nb][i] += fmaxf(acc[mb][nb][i] + bv, 0.f);
    }
  }
  // device-scope f32 atomic accumulate (2 contributors per element)
  #pragma unroll
  for (int nb = 0; nb < 4; nb++) {
    int col = nw + nb * 16 + lrow;
    #pragma unroll
    for (int mb = 0; mb < 2; mb++)
      #pragma unroll
      for (int i = 0; i < 4; i++) {
        int row = b0 + mb * 16 + quad * 4 + i;
        atomicAdd(&g_pooled[(size_t)row * NH + col], pool[mb][nb][i]);
      }
  }
}

// ---------------- rho + heads ---------------------------------------------------
// grid = Bsz/32. g_pooled(f32) -> GEMM3(relu,br) -> heads(N=64) -> clip -> out.
__global__ __launch_bounds__(256)
void rho_heads(const float* __restrict__ br, const float* __restrict__ bm,
               const float* __restrict__ bs, float* __restrict__ out) {
  __shared__ __attribute__((aligned(16))) u16 As2[32][264];
  __shared__ __attribute__((aligned(16))) u16 Bs2[256][72];
  const int b0 = blockIdx.x * 32;
  const int tid = threadIdx.x;
  const int wave = tid >> 6, lane = tid & 63;
  const int nw = wave * 64, lrow = lane & 15, quad = lane >> 4;
  const int srow = tid >> 3, sck = (tid & 7) * 8;

  // stage pooled (f32) -> bf16 A-tile 32x256
  #pragma unroll
  for (int c4 = 0; c4 < 4; c4++) {
    int col = c4 * 64 + sck;
    float f[8];
    load8f(g_pooled + (size_t)(b0 + srow) * NH + col, f);
    *(uint4*)(&As2[srow][col]) = pack8(f);
  }

  const f32x4 vzero = {0.f, 0.f, 0.f, 0.f};
  f32x4 acc[2][4];
  #pragma unroll
  for (int a = 0; a < 2; a++)
    #pragma unroll
    for (int b = 0; b < 4; b++) acc[a][b] = vzero;

  for (int k0 = 0; k0 < 256; k0 += 64) {
    #pragma unroll
    for (int i = 0; i < 8; i++) {
      int row = srow + i * 32;
      *(uint4*)(&Bs2[row][sck]) =
          *(const uint4*)(g_Rt + (size_t)row * 256 + k0 + sck);
    }
    __syncthreads();   // first iter also covers As2 staging
    #pragma unroll
    for (int ks = 0; ks < 2; ks++) {
      int kk = ks * 32 + quad * 8;
      bf16x8 af[2], bq[4];
      af[0] = *(const bf16x8*)(&As2[lrow][k0 + kk]);
      af[1] = *(const bf16x8*)(&As2[16 + lrow][k0 + kk]);
      #pragma unroll
      for (int nb = 0; nb < 4; nb++)
        bq[nb] = *(const bf16x8*)(&Bs2[nw + nb * 16 + lrow][kk]);
      #pragma unroll
      for (int mb = 0; mb < 2; mb++)
        #pragma unroll
        for (int nb = 0; nb < 4; nb++)
          acc[mb][nb] = __builtin_amdgcn_mfma_f32_16x16x32_bf16(
              af[mb], bq[nb], acc[mb][nb], 0, 0, 0);
    }
    __syncthreads();
  }
  // r = bf16(relu(acc + br)) -> back into As2 (reads done at last barrier)
  #pragma unroll
  for (int nb = 0; nb < 4; nb++) {
    int col = nw + nb * 16 + lrow;
    float bv = br[col];
    #pragma unroll
    for (int mb = 0; mb < 2; mb++)
      #pragma unroll
      for (int i = 0; i < 4; i++)
        As2[mb * 16 + quad * 4 + i][col] = f2bf(fmaxf(acc[mb][nb][i] + bv, 0.f));
  }

  // heads: N=64 (mean|log_std); wave w owns 16-col tile w.
  f32x4 acc2[2] = {vzero, vzero};
  for (int k0 = 0; k0 < 256; k0 += 64) {
    {
      int wrow = tid >> 2, wck = (tid & 3) * 16;
      *(uint4*)(&Bs2[wrow][wck]) =
          *(const uint4*)(g_Wcat + (size_t)wrow * NH + k0 + wck);
      *(uint4*)(&Bs2[wrow][wck + 8]) =
          *(const uint4*)(g_Wcat + (size_t)wrow * NH + k0 + wck + 8);
    }
    __syncthreads();   // first iter also covers As2 r-writes
    #pragma unroll
    for (int ks = 0; ks < 2; ks++) {
      int kk = ks * 32 + quad * 8;
      bf16x8 af[2], bq;
      af[0] = *(const bf16x8*)(&As2[lrow][k0 + kk]);
      af[1] = *(const bf16x8*)(&As2[16 + lrow][k0 + kk]);
      bq = *(const bf16x8*)(&Bs2[wave * 16 + lrow][kk]);
      acc2[0] = __builtin_amdgcn_mfma_f32_16x16x32_bf16(af[0], bq, acc2[0], 0, 0, 0);
      acc2[1] = __builtin_amdgcn_mfma_f32_16x16x32_bf16(af[1], bq, acc2[1], 0, 0, 0);
    }
    __syncthreads();
  }
  int j = wave * 16 + lrow;
  #pragma unroll
  for (int mb = 0; mb < 2; mb++) {
    #pragma unroll
    for (int i = 0; i < 4; i++) {
      int b = b0 + mb * 16 + quad * 4 + i;
      if (j < 32) {
        out[(size_t)b * 32 + j] = acc2[mb][i] + bm[j];
      } else {
        float v = acc2[mb][i] + bs[j - 32];
        v = fminf(fmaxf(v, -20.f), 2.f);
        out[(size_t)Bsz * 32 + (size_t)b * 32 + (j - 32)] = v;
      }
    }
  }
}

extern "C" void kernel_launch(void* const* d_in, const int* in_sizes, int n_in,
                              void* d_out, int out_size, void* d_ws, size_t ws_size,
                              hipStream_t stream) {
  const float* obs  = (const float*)d_in[0];
  const float* ef   = (const float*)d_in[1];
  // d_in[2] = edges_to (int32): tile(arange(9),8) -> edge e feeds node e%9
  const float* iso  = (const float*)d_in[3];
  const float* isof = (const float*)d_in[4];
  const float* W1   = (const float*)d_in[5];
  const float* b1   = (const float*)d_in[6];
  const float* W2   = (const float*)d_in[7];
  const float* b2   = (const float*)d_in[8];
  const float* Wr   = (const float*)d_in[9];
  const float* br   = (const float*)d_in[10];
  const float* Wm   = (const float*)d_in[11];
  const float* bm   = (const float*)d_in[12];
  const float* Wsg  = (const float*)d_in[13];
  const float* bs   = (const float*)d_in[14];
  float* out = (float*)d_out;
  (void)d_ws; (void)ws_size;

  transpose_cast<<<dim3(10, 8), 256, 0, stream>>>(W1, 0, 320, 256, 0);
  transpose_cast<<<dim3(8, 8), 256, 0, stream>>>(W2, 1, 256, 256, 0);
  transpose_cast<<<dim3(8, 8), 256, 0, stream>>>(Wr, 2, 256, 256, 0);
  transpose_cast<<<dim3(8, 1), 256, 0, stream>>>(Wm, 3, 256, 32, 0);
  transpose_cast<<<dim3(8, 1), 256, 0, stream>>>(Wsg, 3, 256, 32, 32);
  zero_pooled<<<(Bsz * NH / 4) / 256, 256, 0, stream>>>();

  node_kernel<<<(Bsz / 32) * 2, 256, 0, stream>>>(obs, ef, iso, isof, b1, b2);
  rho_heads<<<Bsz / 32, 256, 0, stream>>>(br, bm, bs, out);
}